// Round 1
// baseline (25299.048 us; speedup 1.0000x reference)
//
#include <hip/hip_runtime.h>

// ---------------------------------------------------------------------------
// 2-layer LSTM, S=512, B=64, I=H=1024 on MI355X.
// Strategy:
//   * G0 = x@Wih0 + (bih0+bhh0) precomputed for all timesteps by a bf16 MFMA
//     GEMM (parallel work), stored bf16 in ws (chunked to fit ws_size).
//   * Persistent kernel (192 blocks, 1/CU, all co-resident): weights live in
//     LDS across all 512 steps. Blocks 0..63 = layer0 (Whh0, K=1024, 16
//     h-cols each); blocks 64..191 = layer1 ([Wih1;Whh1], K=2048, 8 h-cols).
//     Layer1 pipelined one step behind layer0. Device-scope counter flags
//     (release/acquire) synchronize steps; h recurrent state in bf16 global
//     buffers (h0 triple-buffered, h1 double-buffered), c in fp32.
//   * Transposed GEMM: gates[n][b] = sum_k W_T[n][k] * h[b][k], so the
//     LDS-resident weight is the MFMA A operand (contiguous k) and h rows are
//     the B operand loaded directly from global (L2-hot, 128-256 KB).
// ---------------------------------------------------------------------------

typedef unsigned short bhalf;
typedef __attribute__((ext_vector_type(8))) short s8v;    // 8 bf16 = 4 VGPRs
typedef __attribute__((ext_vector_type(4))) float f32x4;  // MFMA acc
typedef __attribute__((ext_vector_type(2))) unsigned int u32x2;

__device__ __forceinline__ float bf2f(bhalf u) {
    unsigned int x = ((unsigned int)u) << 16;
    return __builtin_bit_cast(float, x);
}
__device__ __forceinline__ bhalf f2bf(float f) {
    unsigned int x = __builtin_bit_cast(unsigned int, f);
    unsigned int r = (x + 0x7fffu + ((x >> 16) & 1u)) >> 16;
    return (bhalf)r;
}
__device__ __forceinline__ float sigf(float x) { return 1.f / (1.f + __expf(-x)); }
__device__ __forceinline__ float tanh_(float x) { return 2.f / (1.f + __expf(-2.f * x)) - 1.f; }

__device__ __forceinline__ void waitflag(int* p, int target) {
    int it = 0;
    while (__hip_atomic_load(p, __ATOMIC_ACQUIRE, __HIP_MEMORY_SCOPE_AGENT) < target) {
        __builtin_amdgcn_s_sleep(2);
        if (++it > 40000000) break;  // safety: never hard-hang the bench
    }
}

// --------------------------- init (runs every call) -------------------------
__global__ __launch_bounds__(256) void init_k(
    const float* __restrict__ bih0, const float* __restrict__ bhh0,
    const float* __restrict__ bih1, const float* __restrict__ bhh1,
    float* bias0, float* bias1, bhalf* h0z, bhalf* h1z,
    float* c0, float* c1, int* cnts)
{
    int i = blockIdx.x * 256 + threadIdx.x;  // grid 256 -> 65536 threads
    h0z[i] = 0; h1z[i] = 0; c0[i] = 0.f; c1[i] = 0.f;
    if (i < 1024) cnts[i] = 0;
    if (i < 4096) {
        bias0[i] = bih0[i] + bhh0[i];
        bias1[i] = bih1[i] + bhh1[i];
    }
}

// ---------------- transpose fp32 (1024 x 4096) -> bf16 [n][k] ----------------
__global__ __launch_bounds__(256) void transpose_k(
    const float* __restrict__ src, bhalf* __restrict__ dst, int dstStride, int kOff)
{
    __shared__ float T[64][65];
    int kb = blockIdx.x & 15;   // 1024/64
    int nb = blockIdx.x >> 4;   // 4096/64
    int k0 = kb << 6, n0 = nb << 6;
    int tid = threadIdx.x;
    #pragma unroll
    for (int i = 0; i < 16; ++i) {
        int lin = (i << 8) + tid;
        int r = lin >> 6, c = lin & 63;
        T[r][c] = src[(size_t)(k0 + r) * 4096 + n0 + c];
    }
    __syncthreads();
    #pragma unroll
    for (int i = 0; i < 16; ++i) {
        int lin = (i << 8) + tid;
        int r = lin >> 6, c = lin & 63;   // r = n-local, c = k-local
        dst[(size_t)(n0 + r) * dstStride + kOff + k0 + c] = f2bf(T[c][r]);
    }
}

// ------------- G0 GEMM: G0[row][n] = x[row]@Wih0 + bias0 (bf16 out) ----------
// 128x128 tile, 4 waves (2x2), Kc=64, K=1024. rows are (t*64+b).
__global__ __launch_bounds__(256) void g0gemm_k(
    const float* __restrict__ x, const bhalf* __restrict__ WT,
    const float* __restrict__ bias0, bhalf* __restrict__ G0,
    int t0, int bmCount)
{
    __shared__ __align__(16) bhalf Xs[128 * 72];
    __shared__ __align__(16) bhalf Ws[128 * 72];
    const int tid = threadIdx.x;
    const int bm = blockIdx.x % bmCount;
    const int bn = blockIdx.x / bmCount;
    const int row0 = bm << 7;
    const int n0 = bn << 7;
    const int wid = tid >> 6, lane = tid & 63;
    const int wm = wid >> 1, wn = wid & 1;
    const int row16 = lane & 15, koff = (lane >> 4) << 3;

    f32x4 acc[4][4];
    const f32x4 zero4 = {0.f, 0.f, 0.f, 0.f};
    #pragma unroll
    for (int mt = 0; mt < 4; ++mt)
        #pragma unroll
        for (int nt = 0; nt < 4; ++nt) acc[mt][nt] = zero4;

    const float* xbase = x + (size_t)(t0 * 64 + row0) * 1024;
    for (int kc = 0; kc < 16; ++kc) {
        __syncthreads();
        #pragma unroll
        for (int j = 0; j < 8; ++j) {               // stage X: 128x64 fp32 -> bf16
            int e = (((j << 8) + tid) << 2);
            int r = e >> 6, k = e & 63;
            f32x4 xv = *(const f32x4*)(xbase + (size_t)r * 1024 + (kc << 6) + k);
            u32x2 p;
            p.x = (unsigned)f2bf(xv.x) | ((unsigned)f2bf(xv.y) << 16);
            p.y = (unsigned)f2bf(xv.z) | ((unsigned)f2bf(xv.w) << 16);
            *(u32x2*)&Xs[r * 72 + k] = p;
        }
        #pragma unroll
        for (int j = 0; j < 4; ++j) {               // stage W rows [n][k]
            int e = (((j << 8) + tid) << 3);
            int r = e >> 6, k = e & 63;
            *(s8v*)&Ws[r * 72 + k] = *(const s8v*)(WT + (size_t)(n0 + r) * 1024 + (kc << 6) + k);
        }
        __syncthreads();
        #pragma unroll
        for (int ks = 0; ks < 2; ++ks) {
            int kk = ks << 5;
            s8v a[4], b[4];
            #pragma unroll
            for (int mt = 0; mt < 4; ++mt)
                a[mt] = *(const s8v*)&Xs[(wm * 64 + mt * 16 + row16) * 72 + kk + koff];
            #pragma unroll
            for (int nt = 0; nt < 4; ++nt)
                b[nt] = *(const s8v*)&Ws[(wn * 64 + nt * 16 + row16) * 72 + kk + koff];
            #pragma unroll
            for (int mt = 0; mt < 4; ++mt)
                #pragma unroll
                for (int nt = 0; nt < 4; ++nt)
                    acc[mt][nt] = __builtin_amdgcn_mfma_f32_16x16x32_bf16(a[mt], b[nt], acc[mt][nt], 0, 0, 0);
        }
    }
    #pragma unroll
    for (int mt = 0; mt < 4; ++mt)
        #pragma unroll
        for (int nt = 0; nt < 4; ++nt) {
            int gcol = n0 + wn * 64 + nt * 16 + row16;
            float bz = bias0[gcol];
            #pragma unroll
            for (int r = 0; r < 4; ++r) {
                int grow = row0 + wm * 64 + mt * 16 + ((lane >> 4) << 2) + r;
                G0[((size_t)grow << 12) + gcol] = f2bf(acc[mt][nt][r] + bz);
            }
        }
}

// --------------------------- persistent recurrence ---------------------------
template <bool IS_L0>
__device__ __forceinline__ void rec_loop(
    bhalf* Wlds, float* gatesLds,
    const bhalf* __restrict__ G0, const float* __restrict__ bias1,
    bhalf* h0buf, bhalf* h1buf, float* cws,
    int* cnt0, int* cnt1, float* out,
    int t0, int nsteps, int wgIdx)
{
    constexpr int K = IS_L0 ? 1024 : 2048;
    constexpr int WSTR = IS_L0 ? 1032 : 2056;
    constexpr int NMT = IS_L0 ? 4 : 2;   // 16-wide M(=gate-col) tiles per WG
    constexpr int NH = IS_L0 ? 16 : 8;   // h-cols per WG
    const int tid = threadIdx.x;
    const int wid = tid >> 6, lane = tid & 63;
    const int row16 = lane & 15;
    const int koff = (lane >> 4) << 3;
    const int hcBase = wgIdx * NH;
    const f32x4 zero4 = {0.f, 0.f, 0.f, 0.f};

    for (int tl = 0; tl < nsteps; ++tl) {
        const int t = t0 + tl;
        if (IS_L0) {
            if (tid == 0 && t >= 1) waitflag(&cnt0[t - 1], 64);    // h0(t-1) ready
            if (tid == 64 && t >= 2) waitflag(&cnt1[t - 2], 128);  // h0 buf overwrite safe
        } else {
            if (tid == 0) waitflag(&cnt0[t], 64);                  // h0(t) ready
            if (tid == 64 && t >= 1) waitflag(&cnt1[t - 1], 128);  // h1(t-1) ready
        }
        __syncthreads();
        const bhalf* h0r = h0buf + ((t + 2) % 3) * 65536;  // h0(t-1)
        const bhalf* h0c = h0buf + (t % 3) * 65536;        // h0(t)
        const bhalf* h1r = h1buf + ((t + 1) & 1) * 65536;  // h1(t-1)

        if (wid < 2) {  // waves 0,1 do the GEMM (b-split over batch halves)
            f32x4 acc[NMT][2];
            #pragma unroll
            for (int mt = 0; mt < NMT; ++mt) { acc[mt][0] = zero4; acc[mt][1] = zero4; }
            const int bc0 = (wid << 5) + row16;
            for (int ks = 0; ks < (K >> 5); ++ks) {
                const int kk = ks << 5;
                const bhalf* hsrc; int kl;
                if (IS_L0) { hsrc = h0r; kl = kk; }
                else if (kk < 1024) { hsrc = h0c; kl = kk; }
                else { hsrc = h1r; kl = kk - 1024; }
                s8v b0 = *(const s8v*)(hsrc + bc0 * 1024 + kl + koff);
                s8v b1 = *(const s8v*)(hsrc + (bc0 + 16) * 1024 + kl + koff);
                #pragma unroll
                for (int mt = 0; mt < NMT; ++mt) {
                    s8v a = *(const s8v*)&Wlds[(mt * 16 + row16) * WSTR + kk + koff];
                    acc[mt][0] = __builtin_amdgcn_mfma_f32_16x16x32_bf16(a, b0, acc[mt][0], 0, 0, 0);
                    acc[mt][1] = __builtin_amdgcn_mfma_f32_16x16x32_bf16(a, b1, acc[mt][1], 0, 0, 0);
                }
            }
            #pragma unroll
            for (int mt = 0; mt < NMT; ++mt)
                #pragma unroll
                for (int nt = 0; nt < 2; ++nt)
                    #pragma unroll
                    for (int r = 0; r < 4; ++r) {
                        int ci = mt * 16 + ((lane >> 4) << 2) + r;        // gate-col local
                        int bc = (wid << 5) + (nt << 4) + row16;          // batch
                        gatesLds[ci * 68 + bc] = acc[mt][nt][r];
                    }
        }
        __syncthreads();

        for (int o = tid; o < 64 * NH; o += 256) {
            int b = o / NH;
            int j = o & (NH - 1);
            int hc = hcBase + j;
            float gi = gatesLds[(0 * NH + j) * 68 + b];
            float gf = gatesLds[(1 * NH + j) * 68 + b];
            float go = gatesLds[(2 * NH + j) * 68 + b];
            float gg = gatesLds[(3 * NH + j) * 68 + b];
            if (IS_L0) {
                const bhalf* gp = G0 + (((size_t)tl * 64 + b) << 12) + hc;
                gi += bf2f(gp[0]); gf += bf2f(gp[1024]);
                go += bf2f(gp[2048]); gg += bf2f(gp[3072]);
            } else {
                gi += bias1[hc]; gf += bias1[1024 + hc];
                go += bias1[2048 + hc]; gg += bias1[3072 + hc];
            }
            int ix = (b << 10) + hc;
            float c = sigf(gf) * cws[ix] + sigf(gi) * tanh_(gg);
            cws[ix] = c;
            float h = sigf(go) * tanh_(c);
            if (IS_L0) {
                h0buf[(t % 3) * 65536 + ix] = f2bf(h);
            } else {
                h1buf[(t & 1) * 65536 + ix] = f2bf(h);
                out[(((size_t)t * 64 + b) << 10) + hc] = h;
            }
        }
        __threadfence();
        __syncthreads();
        if (tid == 0)
            __hip_atomic_fetch_add(IS_L0 ? &cnt0[t] : &cnt1[t], 1,
                                   __ATOMIC_RELEASE, __HIP_MEMORY_SCOPE_AGENT);
    }
}

__global__ __launch_bounds__(256) void rec_k(
    const bhalf* __restrict__ W0T, const bhalf* __restrict__ W1T,
    const bhalf* __restrict__ G0, const float* __restrict__ bias1,
    bhalf* h0buf, bhalf* h1buf, float* c0ws, float* c1ws,
    int* cnt0, int* cnt1, float* out, int t0, int nsteps)
{
    __shared__ __align__(16) bhalf Wlds[66048];        // 129 KB: weight slice
    __shared__ __align__(16) float gatesLds[64 * 68];  // 17 KB: gate exchange
    const int tid = threadIdx.x;
    const int wg = blockIdx.x;
    if (wg < 64) {
        // layer0: 64 gate cols = 16 h-cols; LDS row ci -> n=(ci>>4)*1024+wg*16+(ci&15)
        for (int it = 0; it < 32; ++it) {
            int e = (((it << 8) + tid) << 3);
            int ci = e >> 10, k = e & 1023;
            int n = ((ci >> 4) << 10) + (wg << 4) + (ci & 15);
            *(s8v*)&Wlds[ci * 1032 + k] = *(const s8v*)(W0T + ((size_t)n << 10) + k);
        }
        rec_loop<true>(Wlds, gatesLds, G0, bias1, h0buf, h1buf, c0ws, cnt0, cnt1, out, t0, nsteps, wg);
    } else {
        int wg1 = wg - 64;
        // layer1: 32 gate cols = 8 h-cols; ci -> n=(ci>>3)*1024+wg1*8+(ci&7)
        for (int it = 0; it < 32; ++it) {
            int e = (((it << 8) + tid) << 3);
            int ci = e >> 11, k = e & 2047;
            int n = ((ci >> 3) << 10) + (wg1 << 3) + (ci & 7);
            *(s8v*)&Wlds[ci * 2056 + k] = *(const s8v*)(W1T + ((size_t)n << 11) + k);
        }
        rec_loop<false>(Wlds, gatesLds, G0, bias1, h0buf, h1buf, c1ws, cnt0, cnt1, out, t0, nsteps, wg1);
    }
}

// --------------------------------- tail -------------------------------------
__global__ __launch_bounds__(256) void tail_k(
    const bhalf* __restrict__ h0f, const bhalf* __restrict__ h1f,
    const float* __restrict__ c0, const float* __restrict__ c1, float* dst)
{
    int i = blockIdx.x * 256 + threadIdx.x;  // grid 512 -> 131072
    if (i >= 131072) return;
    int l = i >> 16, r = i & 65535;
    dst[i] = bf2f(l ? h1f[r] : h0f[r]);
    dst[131072 + i] = l ? c1[r] : c0[r];
}

// --------------------------------- host -------------------------------------
extern "C" void kernel_launch(void* const* d_in, const int* in_sizes, int n_in,
                              void* d_out, int out_size, void* d_ws, size_t ws_size,
                              hipStream_t stream) {
    const float* x    = (const float*)d_in[0];
    const float* Wih0 = (const float*)d_in[1];
    const float* bih0 = (const float*)d_in[2];
    const float* Whh0 = (const float*)d_in[3];
    const float* bhh0 = (const float*)d_in[4];
    const float* Wih1 = (const float*)d_in[5];
    const float* bih1 = (const float*)d_in[6];
    const float* Whh1 = (const float*)d_in[7];
    const float* bhh1 = (const float*)d_in[8];
    float* out = (float*)d_out;
    char* ws = (char*)d_ws;

    bhalf* WT0ih = (bhalf*)(ws);                    // [4096][1024] bf16
    bhalf* WT0hh = (bhalf*)(ws + 8388608);          // [4096][1024]
    bhalf* WT1   = (bhalf*)(ws + 16777216);         // [4096][2048] = [Wih1;Whh1]
    float* bias0 = (float*)(ws + 33554432);
    float* bias1 = (float*)(ws + 33570816);
    bhalf* h0buf = (bhalf*)(ws + 33587200);         // 3 x (64x1024)
    bhalf* h1buf = (bhalf*)(ws + 33980416);         // 2 x (64x1024)
    float* c0    = (float*)(ws + 34242560);
    float* c1    = (float*)(ws + 34504704);
    int*   cnt0  = (int*)(ws + 34766848);           // [512]
    int*   cnt1  = (int*)(ws + 34768896);           // [512]
    bhalf* G0    = (bhalf*)(ws + 34770944);         // [CHUNK*64][4096] bf16

    const size_t fixedSz = 34770944;
    int CHUNK = 8;
    for (int c = 512; c >= 8; c >>= 1)
        if (fixedSz + (size_t)c * 524288 <= ws_size) { CHUNK = c; break; }

    init_k<<<256, 256, 0, stream>>>(bih0, bhh0, bih1, bhh1, bias0, bias1,
                                    h0buf + 2 * 65536, h1buf + 1 * 65536, c0, c1, cnt0);
    transpose_k<<<1024, 256, 0, stream>>>(Wih0, WT0ih, 1024, 0);
    transpose_k<<<1024, 256, 0, stream>>>(Whh0, WT0hh, 1024, 0);
    transpose_k<<<1024, 256, 0, stream>>>(Wih1, WT1, 2048, 0);
    transpose_k<<<1024, 256, 0, stream>>>(Whh1, WT1, 2048, 1024);

    for (int t0 = 0; t0 < 512; t0 += CHUNK) {
        int bmCount = CHUNK / 2;
        g0gemm_k<<<bmCount * 32, 256, 0, stream>>>(x, WT0ih, bias0, G0, t0, bmCount);
        rec_k<<<192, 256, 0, stream>>>(WT0hh, WT1, G0, bias1, h0buf, h1buf,
                                       c0, c1, cnt0, cnt1, out, t0, CHUNK);
    }
    // final h: h0(511) in buf (511%3)=1 ; h1(511) in buf (511&1)=1
    tail_k<<<512, 256, 0, stream>>>(h0buf + 1 * 65536, h1buf + 1 * 65536,
                                    c0, c1, out + 33554432);
}

// Round 2
// 9530.456 us; speedup vs baseline: 2.6545x; 2.6545x over previous
//
#include <hip/hip_runtime.h>

// ---------------------------------------------------------------------------
// 2-layer LSTM, S=512, B=64, I=H=1024 on MI355X.
//   * G0 = x@Wih0 + (bih0+bhh0) precomputed by bf16 MFMA GEMM into ws.
//   * Persistent rec_k (192 blocks, 1/CU): weights LDS-resident all 512 steps
//     in a lane-linear swizzled layout (conflict-free A-frag reads).
//     Blocks 0..63 = layer0 (Whh0, K=1024); 64..191 = layer1 ([Wih1;Whh1],
//     K=2048, one step behind).
//   * Sync: per-block flag (own cacheline), published with relaxed agent
//     store after vmcnt(0); h published via packed 4B relaxed agent stores
//     (write-through to LLC). Readers: parallel relaxed polls (1 flag/lane),
//     then ONE acquire fence (buffer_inv) per step, then normal cached loads.
//     No contended atomics, no per-step wbl2, no per-poll invalidates.
//   * c state lives in registers (block-private), persisted only at chunk
//     boundaries.
// ---------------------------------------------------------------------------

typedef unsigned short bhalf;
typedef __attribute__((ext_vector_type(8))) short s8v;    // 8 bf16 = 4 VGPRs
typedef __attribute__((ext_vector_type(4))) float f32x4;  // MFMA acc
typedef __attribute__((ext_vector_type(2))) unsigned int u32x2;

__device__ __forceinline__ float bf2f(bhalf u) {
    unsigned int x = ((unsigned int)u) << 16;
    return __builtin_bit_cast(float, x);
}
__device__ __forceinline__ bhalf f2bf(float f) {
    unsigned int x = __builtin_bit_cast(unsigned int, f);
    unsigned int r = (x + 0x7fffu + ((x >> 16) & 1u)) >> 16;
    return (bhalf)r;
}
__device__ __forceinline__ float sigf(float x) { return 1.f / (1.f + __expf(-x)); }
__device__ __forceinline__ float tanh_(float x) { return 2.f / (1.f + __expf(-2.f * x)) - 1.f; }

// relaxed agent-scope poll: LLC-direct load, no cache maintenance per spin
__device__ __forceinline__ void pollge(const int* p, int target) {
    if (target <= 0) return;
    int it = 0;
    while (__hip_atomic_load(p, __ATOMIC_RELAXED, __HIP_MEMORY_SCOPE_AGENT) < target) {
        __builtin_amdgcn_s_sleep(1);
        if (++it > 50000000) break;  // safety: never hard-hang the bench
    }
}

// --------------------------- init (runs every call) -------------------------
__global__ __launch_bounds__(256) void init_k(
    const float* __restrict__ bih0, const float* __restrict__ bhh0,
    const float* __restrict__ bih1, const float* __restrict__ bhh1,
    float* bias0, float* bias1, bhalf* h0z, bhalf* h1z,
    float* c0, float* c1, int* flags)
{
    int i = blockIdx.x * 256 + threadIdx.x;  // grid 256 -> 65536 threads
    h0z[i] = 0; h1z[i] = 0; c0[i] = 0.f; c1[i] = 0.f;
    if (i < 6144) flags[i] = 0;              // done0[64*32] + done1[128*32]
    if (i < 4096) {
        bias0[i] = bih0[i] + bhh0[i];
        bias1[i] = bih1[i] + bhh1[i];
    }
}

// ---------------- transpose fp32 (1024 x 4096) -> bf16 [n][k] ----------------
__global__ __launch_bounds__(256) void transpose_k(
    const float* __restrict__ src, bhalf* __restrict__ dst, int dstStride, int kOff)
{
    __shared__ float T[64][65];
    int kb = blockIdx.x & 15;   // 1024/64
    int nb = blockIdx.x >> 4;   // 4096/64
    int k0 = kb << 6, n0 = nb << 6;
    int tid = threadIdx.x;
    #pragma unroll
    for (int i = 0; i < 16; ++i) {
        int lin = (i << 8) + tid;
        int r = lin >> 6, c = lin & 63;
        T[r][c] = src[(size_t)(k0 + r) * 4096 + n0 + c];
    }
    __syncthreads();
    #pragma unroll
    for (int i = 0; i < 16; ++i) {
        int lin = (i << 8) + tid;
        int r = lin >> 6, c = lin & 63;   // r = n-local, c = k-local
        dst[(size_t)(n0 + r) * dstStride + kOff + k0 + c] = f2bf(T[c][r]);
    }
}

// ------------- G0 GEMM: G0[row][n] = x[row]@Wih0 + bias0 (bf16 out) ----------
__global__ __launch_bounds__(256) void g0gemm_k(
    const float* __restrict__ x, const bhalf* __restrict__ WT,
    const float* __restrict__ bias0, bhalf* __restrict__ G0,
    int t0, int bmCount)
{
    __shared__ __align__(16) bhalf Xs[128 * 72];
    __shared__ __align__(16) bhalf Ws[128 * 72];
    const int tid = threadIdx.x;
    const int bm = blockIdx.x % bmCount;
    const int bn = blockIdx.x / bmCount;
    const int row0 = bm << 7;
    const int n0 = bn << 7;
    const int wid = tid >> 6, lane = tid & 63;
    const int wm = wid >> 1, wn = wid & 1;
    const int row16 = lane & 15, koff = (lane >> 4) << 3;

    f32x4 acc[4][4];
    const f32x4 zero4 = {0.f, 0.f, 0.f, 0.f};
    #pragma unroll
    for (int mt = 0; mt < 4; ++mt)
        #pragma unroll
        for (int nt = 0; nt < 4; ++nt) acc[mt][nt] = zero4;

    const float* xbase = x + (size_t)(t0 * 64 + row0) * 1024;
    for (int kc = 0; kc < 16; ++kc) {
        __syncthreads();
        #pragma unroll
        for (int j = 0; j < 8; ++j) {               // stage X: 128x64 fp32 -> bf16
            int e = (((j << 8) + tid) << 2);
            int r = e >> 6, k = e & 63;
            f32x4 xv = *(const f32x4*)(xbase + (size_t)r * 1024 + (kc << 6) + k);
            u32x2 p;
            p.x = (unsigned)f2bf(xv.x) | ((unsigned)f2bf(xv.y) << 16);
            p.y = (unsigned)f2bf(xv.z) | ((unsigned)f2bf(xv.w) << 16);
            *(u32x2*)&Xs[r * 72 + k] = p;
        }
        #pragma unroll
        for (int j = 0; j < 4; ++j) {               // stage W rows [n][k]
            int e = (((j << 8) + tid) << 3);
            int r = e >> 6, k = e & 63;
            *(s8v*)&Ws[r * 72 + k] = *(const s8v*)(WT + (size_t)(n0 + r) * 1024 + (kc << 6) + k);
        }
        __syncthreads();
        #pragma unroll
        for (int ks = 0; ks < 2; ++ks) {
            int kk = ks << 5;
            s8v a[4], b[4];
            #pragma unroll
            for (int mt = 0; mt < 4; ++mt)
                a[mt] = *(const s8v*)&Xs[(wm * 64 + mt * 16 + row16) * 72 + kk + koff];
            #pragma unroll
            for (int nt = 0; nt < 4; ++nt)
                b[nt] = *(const s8v*)&Ws[(wn * 64 + nt * 16 + row16) * 72 + kk + koff];
            #pragma unroll
            for (int mt = 0; mt < 4; ++mt)
                #pragma unroll
                for (int nt = 0; nt < 4; ++nt)
                    acc[mt][nt] = __builtin_amdgcn_mfma_f32_16x16x32_bf16(a[mt], b[nt], acc[mt][nt], 0, 0, 0);
        }
    }
    #pragma unroll
    for (int mt = 0; mt < 4; ++mt)
        #pragma unroll
        for (int nt = 0; nt < 4; ++nt) {
            int gcol = n0 + wn * 64 + nt * 16 + row16;
            float bz = bias0[gcol];
            #pragma unroll
            for (int r = 0; r < 4; ++r) {
                int grow = row0 + wm * 64 + mt * 16 + ((lane >> 4) << 2) + r;
                G0[((size_t)grow << 12) + gcol] = f2bf(acc[mt][nt][r] + bz);
            }
        }
}

// --------------------------- persistent recurrence ---------------------------
template <bool IS_L0>
__device__ __forceinline__ void rec_loop(
    const bhalf* Wlds, float* gatesLds,
    const bhalf* __restrict__ G0, const float* __restrict__ bias1,
    bhalf* h0buf, bhalf* h1buf, float* cws,
    int* done0, int* done1, float* out,
    int t0, int nsteps, int wgIdx)
{
    constexpr int KC32 = IS_L0 ? 32 : 64;   // K/32
    constexpr int NMT  = IS_L0 ? 4 : 2;     // 16-wide gate-col tiles
    constexpr int NH   = IS_L0 ? 16 : 8;    // h-cols per WG
    constexpr int NPIT = IS_L0 ? 2 : 1;     // epilogue pair-iterations
    const int tid = threadIdx.x;
    const int wid = tid >> 6, lane = tid & 63;
    const int row16 = lane & 15;
    const int koff = (lane >> 4) << 3;
    const int hcBase = wgIdx * NH;
    const f32x4 zero4 = {0.f, 0.f, 0.f, 0.f};

    // block-private cell state in registers; persisted only at chunk bounds
    float creg[NPIT][2];
    #pragma unroll
    for (int i2 = 0; i2 < NPIT; ++i2) {
        int p = tid + (i2 << 8);
        int b = p / (NH >> 1), jp = p % (NH >> 1);
        int hc = hcBase + (jp << 1);
        creg[i2][0] = cws[(b << 10) + hc];
        creg[i2][1] = cws[(b << 10) + hc + 1];
    }
    int* myflag = IS_L0 ? &done0[wgIdx * 32] : &done1[wgIdx * 32];

    for (int tl = 0; tl < nsteps; ++tl) {
        const int t = t0 + tl;
        // flag semantics: done[b] == s+1  <=>  block b finished step s
        if (wid == 0)      pollge(&done0[lane * 32], IS_L0 ? t : t + 1);
        else if (wid == 1) pollge(&done1[lane * 32], IS_L0 ? t - 2 : t);
        else if (wid == 2) pollge(&done1[(64 + lane) * 32], IS_L0 ? t - 2 : t);
        __syncthreads();
        __builtin_amdgcn_fence(__ATOMIC_ACQUIRE, "agent");  // one buffer_inv/step

        const bhalf* h0r = h0buf + ((t + 2) % 3) * 65536;  // h0(t-1)
        const bhalf* h0c = h0buf + (t % 3) * 65536;        // h0(t)
        const bhalf* h1r = h1buf + ((t + 1) & 1) * 65536;  // h1(t-1)

        // GEMM: all 4 waves; wave w covers batch [w*16, w*16+16)
        {
            f32x4 acc[NMT];
            #pragma unroll
            for (int mt = 0; mt < NMT; ++mt) acc[mt] = zero4;
            const int brow = (wid << 4) + row16;
            for (int ks = 0; ks < KC32; ++ks) {
                const int kk = ks << 5;
                const bhalf* hsrc; int kl;
                if (IS_L0) { hsrc = h0r; kl = kk; }
                else if (kk < 1024) { hsrc = h0c; kl = kk; }
                else { hsrc = h1r; kl = kk - 1024; }
                s8v bf = *(const s8v*)(hsrc + brow * 1024 + kl + koff);
                #pragma unroll
                for (int mt = 0; mt < NMT; ++mt) {
                    s8v a = *(const s8v*)&Wlds[((((mt * KC32) + ks) << 6) + lane) << 3];
                    acc[mt] = __builtin_amdgcn_mfma_f32_16x16x32_bf16(a, bf, acc[mt], 0, 0, 0);
                }
            }
            #pragma unroll
            for (int mt = 0; mt < NMT; ++mt)
                #pragma unroll
                for (int r = 0; r < 4; ++r) {
                    int ci = (mt << 4) + ((lane >> 4) << 2) + r;  // gate-col local
                    int b = (wid << 4) + row16;                    // batch
                    gatesLds[ci * 68 + b] = acc[mt][r];
                }
        }
        __syncthreads();

        // epilogue: pairs of adjacent h-cols so h publishes as packed 4B
        #pragma unroll
        for (int i2 = 0; i2 < NPIT; ++i2) {
            const int p = tid + (i2 << 8);
            const int b = p / (NH >> 1);
            const int jp = p % (NH >> 1);
            const int j = jp << 1;
            const int hc = hcBase + j;
            float ga[4][2];
            #pragma unroll
            for (int g = 0; g < 4; ++g) {
                ga[g][0] = gatesLds[(g * NH + j) * 68 + b];
                ga[g][1] = gatesLds[(g * NH + j + 1) * 68 + b];
            }
            if (IS_L0) {
                const unsigned* gp = (const unsigned*)(G0 + (((size_t)tl * 64 + b) << 12) + hc);
                #pragma unroll
                for (int g = 0; g < 4; ++g) {
                    unsigned w = gp[g * 512];
                    ga[g][0] += bf2f((bhalf)(w & 0xffffu));
                    ga[g][1] += bf2f((bhalf)(w >> 16));
                }
            } else {
                #pragma unroll
                for (int g = 0; g < 4; ++g) {
                    ga[g][0] += bias1[(g << 10) + hc];
                    ga[g][1] += bias1[(g << 10) + hc + 1];
                }
            }
            float hv[2];
            #pragma unroll
            for (int cix = 0; cix < 2; ++cix) {
                float cn = sigf(ga[1][cix]) * creg[i2][cix] + sigf(ga[0][cix]) * tanh_(ga[3][cix]);
                creg[i2][cix] = cn;
                hv[cix] = sigf(ga[2][cix]) * tanh_(cn);
            }
            unsigned hp = (unsigned)f2bf(hv[0]) | ((unsigned)f2bf(hv[1]) << 16);
            const int ix = (b << 10) + hc;
            if (IS_L0) {
                __hip_atomic_store((unsigned*)(h0buf + (t % 3) * 65536 + ix), hp,
                                   __ATOMIC_RELAXED, __HIP_MEMORY_SCOPE_AGENT);
            } else {
                __hip_atomic_store((unsigned*)(h1buf + (t & 1) * 65536 + ix), hp,
                                   __ATOMIC_RELAXED, __HIP_MEMORY_SCOPE_AGENT);
                float* op = out + (((size_t)t * 64 + b) << 10) + hc;
                op[0] = hv[0]; op[1] = hv[1];
            }
        }
        // publish: all write-through stores acked, then flag (own cacheline)
        asm volatile("s_waitcnt vmcnt(0)" ::: "memory");
        __syncthreads();
        if (tid == 0)
            __hip_atomic_store(myflag, t + 1, __ATOMIC_RELAXED, __HIP_MEMORY_SCOPE_AGENT);
    }

    // persist c for next chunk / tail
    #pragma unroll
    for (int i2 = 0; i2 < NPIT; ++i2) {
        int p = tid + (i2 << 8);
        int b = p / (NH >> 1), jp = p % (NH >> 1);
        int hc = hcBase + (jp << 1);
        cws[(b << 10) + hc]     = creg[i2][0];
        cws[(b << 10) + hc + 1] = creg[i2][1];
    }
}

__global__ __launch_bounds__(256) void rec_k(
    const bhalf* __restrict__ W0T, const bhalf* __restrict__ W1T,
    const bhalf* __restrict__ G0, const float* __restrict__ bias1,
    bhalf* h0buf, bhalf* h1buf, float* c0ws, float* c1ws,
    int* done0, int* done1, float* out, int t0, int nsteps)
{
    __shared__ __align__(16) bhalf Wlds[65536];        // 128 KB swizzled weights
    __shared__ __align__(16) float gatesLds[64 * 68];  // 17 KB gate exchange
    const int tid = threadIdx.x;
    const int wg = blockIdx.x;
    if (wg < 64) {
        // layer0: 64 gate-cols (16 h-cols); swizzle to lane-linear frag order
        for (int it = 0; it < 32; ++it) {
            int e = (((it << 8) + tid) << 3);
            int ci = e >> 10, k0 = e & 1023;
            int n = ((ci >> 4) << 10) + (wg << 4) + (ci & 15);
            int mt = ci >> 4, m = ci & 15, ks = k0 >> 5, q = (k0 >> 3) & 3;
            int off = ((((mt << 5) + ks) << 6) + (q << 4) + m) << 3;
            *(s8v*)&Wlds[off] = *(const s8v*)(W0T + ((size_t)n << 10) + k0);
        }
        rec_loop<true>(Wlds, gatesLds, G0, bias1, h0buf, h1buf, c0ws,
                       done0, done1, out, t0, nsteps, wg);
    } else {
        int wg1 = wg - 64;
        // layer1: 32 gate-cols (8 h-cols), K=2048
        for (int it = 0; it < 32; ++it) {
            int e = (((it << 8) + tid) << 3);
            int ci = e >> 11, k0 = e & 2047;
            int n = ((ci >> 3) << 10) + (wg1 << 3) + (ci & 7);
            int mt = ci >> 4, m = ci & 15, ks = k0 >> 5, q = (k0 >> 3) & 3;
            int off = ((((mt << 6) + ks) << 6) + (q << 4) + m) << 3;
            *(s8v*)&Wlds[off] = *(const s8v*)(W1T + ((size_t)n << 11) + k0);
        }
        rec_loop<false>(Wlds, gatesLds, G0, bias1, h0buf, h1buf, c1ws,
                        done0, done1, out, t0, nsteps, wg1);
    }
}

// --------------------------------- tail -------------------------------------
__global__ __launch_bounds__(256) void tail_k(
    const bhalf* __restrict__ h0f, const bhalf* __restrict__ h1f,
    const float* __restrict__ c0, const float* __restrict__ c1, float* dst)
{
    int i = blockIdx.x * 256 + threadIdx.x;  // grid 512 -> 131072
    if (i >= 131072) return;
    int l = i >> 16, r = i & 65535;
    dst[i] = bf2f(l ? h1f[r] : h0f[r]);
    dst[131072 + i] = l ? c1[r] : c0[r];
}

// --------------------------------- host -------------------------------------
extern "C" void kernel_launch(void* const* d_in, const int* in_sizes, int n_in,
                              void* d_out, int out_size, void* d_ws, size_t ws_size,
                              hipStream_t stream) {
    const float* x    = (const float*)d_in[0];
    const float* Wih0 = (const float*)d_in[1];
    const float* bih0 = (const float*)d_in[2];
    const float* Whh0 = (const float*)d_in[3];
    const float* bhh0 = (const float*)d_in[4];
    const float* Wih1 = (const float*)d_in[5];
    const float* bih1 = (const float*)d_in[6];
    const float* Whh1 = (const float*)d_in[7];
    const float* bhh1 = (const float*)d_in[8];
    float* out = (float*)d_out;
    char* ws = (char*)d_ws;

    bhalf* WT0ih = (bhalf*)(ws);                    // [4096][1024] bf16
    bhalf* WT0hh = (bhalf*)(ws + 8388608);          // [4096][1024]
    bhalf* WT1   = (bhalf*)(ws + 16777216);         // [4096][2048] = [Wih1;Whh1]
    float* bias0 = (float*)(ws + 33554432);
    float* bias1 = (float*)(ws + 33570816);
    bhalf* h0buf = (bhalf*)(ws + 33587200);         // 3 x (64x1024)
    bhalf* h1buf = (bhalf*)(ws + 33980416);         // 2 x (64x1024)
    float* c0    = (float*)(ws + 34242560);
    float* c1    = (float*)(ws + 34504704);
    int*   done0 = (int*)(ws + 34766848);           // 64 x 32 ints (128B apart)
    int*   done1 = (int*)(ws + 34775040);           // 128 x 32 ints
    bhalf* G0    = (bhalf*)(ws + 34791424);         // [CHUNK*64][4096] bf16

    const size_t fixedSz = 34791424;
    int CHUNK = 8;
    for (int c = 512; c >= 8; c >>= 1)
        if (fixedSz + (size_t)c * 524288 <= ws_size) { CHUNK = c; break; }

    init_k<<<256, 256, 0, stream>>>(bih0, bhh0, bih1, bhh1, bias0, bias1,
                                    h0buf + 2 * 65536, h1buf + 1 * 65536, c0, c1, done0);
    transpose_k<<<1024, 256, 0, stream>>>(Wih0, WT0ih, 1024, 0);
    transpose_k<<<1024, 256, 0, stream>>>(Whh0, WT0hh, 1024, 0);
    transpose_k<<<1024, 256, 0, stream>>>(Wih1, WT1, 2048, 0);
    transpose_k<<<1024, 256, 0, stream>>>(Whh1, WT1, 2048, 1024);

    for (int t0 = 0; t0 < 512; t0 += CHUNK) {
        int bmCount = CHUNK / 2;
        g0gemm_k<<<bmCount * 32, 256, 0, stream>>>(x, WT0ih, bias0, G0, t0, bmCount);
        rec_k<<<192, 256, 0, stream>>>(WT0hh, WT1, G0, bias1, h0buf, h1buf,
                                       c0, c1, done0, done1, out, t0, CHUNK);
    }
    // final h: h0(511) in slot (511%3)=1 ; h1(511) in slot (511&1)=1
    tail_k<<<512, 256, 0, stream>>>(h0buf + 1 * 65536, h1buf + 1 * 65536,
                                    c0, c1, out + 33554432);
}

// Round 3
// 9314.726 us; speedup vs baseline: 2.7160x; 1.0232x over previous
//
#include <hip/hip_runtime.h>

// ---------------------------------------------------------------------------
// 2-layer LSTM, S=512, B=64, I=H=1024 on MI355X.
//   * G0 = x@Wih0 + (bih0+bhh0) precomputed by bf16 MFMA GEMM into ws.
//   * Persistent rec_k (192 blocks, 1/CU): weights LDS-resident all 512 steps
//     (lane-linear swizzled, conflict-free). Blocks 0..63 = layer0 (Whh0,
//     K=1024); 64..191 = layer1 ([Wih1;Whh1], K=2048, one step behind).
//   * Sync: per-block flag cacheline, relaxed agent stores after vmcnt(0);
//     readers poll 1 flag/lane relaxed, then ONE acquire fence per step.
//   * Round 3: bulk-load ALL B-fragments into registers before the MFMA loop
//     (one LLC round trip instead of 32-64 serialized ones), prefetch G0
//     before the poll, hoist bias1 to registers, 8B packed h publishes.
//     __launch_bounds__(256,1) -> 512 VGPRs/wave for the B-frag arrays.
// ---------------------------------------------------------------------------

typedef unsigned short bhalf;
typedef __attribute__((ext_vector_type(8))) short s8v;    // 8 bf16 = 4 VGPRs
typedef __attribute__((ext_vector_type(4))) float f32x4;  // MFMA acc
typedef __attribute__((ext_vector_type(2))) unsigned int u32x2;

__device__ __forceinline__ float bf2f(bhalf u) {
    unsigned int x = ((unsigned int)u) << 16;
    return __builtin_bit_cast(float, x);
}
__device__ __forceinline__ bhalf f2bf(float f) {
    unsigned int x = __builtin_bit_cast(unsigned int, f);
    unsigned int r = (x + 0x7fffu + ((x >> 16) & 1u)) >> 16;
    return (bhalf)r;
}
__device__ __forceinline__ float sigf(float x) { return 1.f / (1.f + __expf(-x)); }
__device__ __forceinline__ float tanh_(float x) { return 2.f / (1.f + __expf(-2.f * x)) - 1.f; }

// relaxed agent-scope poll: LLC-direct load, no cache maintenance per spin
__device__ __forceinline__ void pollge(const int* p, int target) {
    if (target <= 0) return;
    int it = 0;
    while (__hip_atomic_load(p, __ATOMIC_RELAXED, __HIP_MEMORY_SCOPE_AGENT) < target) {
        __builtin_amdgcn_s_sleep(1);
        if (++it > 50000000) break;  // safety: never hard-hang the bench
    }
}

// --------------------------- init (runs every call) -------------------------
__global__ __launch_bounds__(256) void init_k(
    const float* __restrict__ bih0, const float* __restrict__ bhh0,
    const float* __restrict__ bih1, const float* __restrict__ bhh1,
    float* bias0, float* bias1, bhalf* h0z, bhalf* h1z,
    float* c0, float* c1, int* flags)
{
    int i = blockIdx.x * 256 + threadIdx.x;  // grid 256 -> 65536 threads
    h0z[i] = 0; h1z[i] = 0; c0[i] = 0.f; c1[i] = 0.f;
    if (i < 6144) flags[i] = 0;              // done0[64*32] + done1[128*32]
    if (i < 4096) {
        bias0[i] = bih0[i] + bhh0[i];
        bias1[i] = bih1[i] + bhh1[i];
    }
}

// ---------------- transpose fp32 (1024 x 4096) -> bf16 [n][k] ----------------
__global__ __launch_bounds__(256) void transpose_k(
    const float* __restrict__ src, bhalf* __restrict__ dst, int dstStride, int kOff)
{
    __shared__ float T[64][65];
    int kb = blockIdx.x & 15;   // 1024/64
    int nb = blockIdx.x >> 4;   // 4096/64
    int k0 = kb << 6, n0 = nb << 6;
    int tid = threadIdx.x;
    #pragma unroll
    for (int i = 0; i < 16; ++i) {
        int lin = (i << 8) + tid;
        int r = lin >> 6, c = lin & 63;
        T[r][c] = src[(size_t)(k0 + r) * 4096 + n0 + c];
    }
    __syncthreads();
    #pragma unroll
    for (int i = 0; i < 16; ++i) {
        int lin = (i << 8) + tid;
        int r = lin >> 6, c = lin & 63;   // r = n-local, c = k-local
        dst[(size_t)(n0 + r) * dstStride + kOff + k0 + c] = f2bf(T[c][r]);
    }
}

// ------------- G0 GEMM: G0[row][n] = x[row]@Wih0 + bias0 (bf16 out) ----------
__global__ __launch_bounds__(256) void g0gemm_k(
    const float* __restrict__ x, const bhalf* __restrict__ WT,
    const float* __restrict__ bias0, bhalf* __restrict__ G0,
    int t0, int bmCount)
{
    __shared__ __align__(16) bhalf Xs[128 * 72];
    __shared__ __align__(16) bhalf Ws[128 * 72];
    const int tid = threadIdx.x;
    const int bm = blockIdx.x % bmCount;
    const int bn = blockIdx.x / bmCount;
    const int row0 = bm << 7;
    const int n0 = bn << 7;
    const int wid = tid >> 6, lane = tid & 63;
    const int wm = wid >> 1, wn = wid & 1;
    const int row16 = lane & 15, koff = (lane >> 4) << 3;

    f32x4 acc[4][4];
    const f32x4 zero4 = {0.f, 0.f, 0.f, 0.f};
    #pragma unroll
    for (int mt = 0; mt < 4; ++mt)
        #pragma unroll
        for (int nt = 0; nt < 4; ++nt) acc[mt][nt] = zero4;

    const float* xbase = x + (size_t)(t0 * 64 + row0) * 1024;
    for (int kc = 0; kc < 16; ++kc) {
        __syncthreads();
        #pragma unroll
        for (int j = 0; j < 8; ++j) {               // stage X: 128x64 fp32 -> bf16
            int e = (((j << 8) + tid) << 2);
            int r = e >> 6, k = e & 63;
            f32x4 xv = *(const f32x4*)(xbase + (size_t)r * 1024 + (kc << 6) + k);
            u32x2 p;
            p.x = (unsigned)f2bf(xv.x) | ((unsigned)f2bf(xv.y) << 16);
            p.y = (unsigned)f2bf(xv.z) | ((unsigned)f2bf(xv.w) << 16);
            *(u32x2*)&Xs[r * 72 + k] = p;
        }
        #pragma unroll
        for (int j = 0; j < 4; ++j) {               // stage W rows [n][k]
            int e = (((j << 8) + tid) << 3);
            int r = e >> 6, k = e & 63;
            *(s8v*)&Ws[r * 72 + k] = *(const s8v*)(WT + (size_t)(n0 + r) * 1024 + (kc << 6) + k);
        }
        __syncthreads();
        #pragma unroll
        for (int ks = 0; ks < 2; ++ks) {
            int kk = ks << 5;
            s8v a[4], b[4];
            #pragma unroll
            for (int mt = 0; mt < 4; ++mt)
                a[mt] = *(const s8v*)&Xs[(wm * 64 + mt * 16 + row16) * 72 + kk + koff];
            #pragma unroll
            for (int nt = 0; nt < 4; ++nt)
                b[nt] = *(const s8v*)&Ws[(wn * 64 + nt * 16 + row16) * 72 + kk + koff];
            #pragma unroll
            for (int mt = 0; mt < 4; ++mt)
                #pragma unroll
                for (int nt = 0; nt < 4; ++nt)
                    acc[mt][nt] = __builtin_amdgcn_mfma_f32_16x16x32_bf16(a[mt], b[nt], acc[mt][nt], 0, 0, 0);
        }
    }
    #pragma unroll
    for (int mt = 0; mt < 4; ++mt)
        #pragma unroll
        for (int nt = 0; nt < 4; ++nt) {
            int gcol = n0 + wn * 64 + nt * 16 + row16;
            float bz = bias0[gcol];
            #pragma unroll
            for (int r = 0; r < 4; ++r) {
                int grow = row0 + wm * 64 + mt * 16 + ((lane >> 4) << 2) + r;
                G0[((size_t)grow << 12) + gcol] = f2bf(acc[mt][nt][r] + bz);
            }
        }
}

// --------------------------- persistent recurrence ---------------------------
template <bool IS_L0>
__device__ __forceinline__ void rec_loop(
    const bhalf* Wlds, float* gatesLds,
    const bhalf* __restrict__ G0, const float* __restrict__ bias1,
    bhalf* h0buf, bhalf* h1buf, float* cws,
    int* done0, int* done1, float* out,
    int t0, int nsteps, int wgIdx)
{
    constexpr int NMT = IS_L0 ? 4 : 2;     // 16-wide gate-col tiles
    constexpr int NH  = IS_L0 ? 16 : 8;    // h-cols per WG
    const int tid = threadIdx.x;
    const int wid = tid >> 6, lane = tid & 63;
    const int row16 = lane & 15;
    const int koff = (lane >> 4) << 3;
    const int hcBase = wgIdx * NH;
    const f32x4 zero4 = {0.f, 0.f, 0.f, 0.f};

    // epilogue geometry: 4 adjacent h-cols per thread
    const bool ep_active = IS_L0 ? true : (tid < 128);
    const int eb  = IS_L0 ? (tid >> 2) : (tid >> 1);
    const int ejq = (IS_L0 ? (tid & 3) : (tid & 1)) << 2;
    const int ehc = hcBase + ejq;

    float creg[4] = {0.f, 0.f, 0.f, 0.f};
    float breg[4][4];
    if (ep_active) {
        #pragma unroll
        for (int j = 0; j < 4; ++j) creg[j] = cws[(eb << 10) + ehc + j];
        if (!IS_L0)
            #pragma unroll
            for (int g = 0; g < 4; ++g)
                #pragma unroll
                for (int j = 0; j < 4; ++j) breg[g][j] = bias1[(g << 10) + ehc + j];
    }
    int* myflag = IS_L0 ? &done0[wgIdx * 32] : &done1[wgIdx * 32];

    for (int tl = 0; tl < nsteps; ++tl) {
        const int t = t0 + tl;

        // prefetch G0 for this step BEFORE polling (chunk-static data)
        u32x2 g0pre[4];
        if (IS_L0) {
            const bhalf* gp = G0 + (((size_t)tl * 64 + eb) << 12) + ehc;
            #pragma unroll
            for (int g = 0; g < 4; ++g) g0pre[g] = *(const u32x2*)(gp + (g << 10));
        }

        // flag semantics: done[b] == s+1  <=>  block b finished step s
        if (wid == 0)      pollge(&done0[lane * 32], IS_L0 ? t : t + 1);
        else if (wid == 1) pollge(&done1[lane * 32], IS_L0 ? t - 2 : t);
        else if (wid == 2) pollge(&done1[(64 + lane) * 32], IS_L0 ? t - 2 : t);
        __syncthreads();
        __builtin_amdgcn_fence(__ATOMIC_ACQUIRE, "agent");  // one buffer_inv/step

        const bhalf* h0r = h0buf + ((t + 2) % 3) * 65536;  // h0(t-1)
        const bhalf* h0c = h0buf + (t % 3) * 65536;        // h0(t)
        const bhalf* h1r = h1buf + ((t + 1) & 1) * 65536;  // h1(t-1)
        const int brow = (wid << 4) + row16;               // batch row (wave-split)

        f32x4 acc[NMT];
        #pragma unroll
        for (int mt = 0; mt < NMT; ++mt) acc[mt] = zero4;

        if (IS_L0) {
            // bulk-load all 32 B-frags (one LLC round trip), then MFMA
            s8v bfr[32];
            #pragma unroll
            for (int ks = 0; ks < 32; ++ks)
                bfr[ks] = *(const s8v*)(h0r + brow * 1024 + (ks << 5) + koff);
            #pragma unroll
            for (int ks = 0; ks < 32; ++ks)
                #pragma unroll
                for (int mt = 0; mt < 4; ++mt) {
                    s8v a = *(const s8v*)&Wlds[((((mt << 5) + ks) << 6) + lane) << 3];
                    acc[mt] = __builtin_amdgcn_mfma_f32_16x16x32_bf16(a, bfr[ks], acc[mt], 0, 0, 0);
                }
        } else {
            // pass0: k 0..1023 from h0(t); pass1: k 1024..2047 from h1(t-1)
            s8v bfa[32], bfb[32];
            #pragma unroll
            for (int ks = 0; ks < 32; ++ks)
                bfa[ks] = *(const s8v*)(h0c + brow * 1024 + (ks << 5) + koff);
            #pragma unroll
            for (int ks = 0; ks < 32; ++ks)
                bfb[ks] = *(const s8v*)(h1r + brow * 1024 + (ks << 5) + koff);
            #pragma unroll
            for (int ks = 0; ks < 32; ++ks)
                #pragma unroll
                for (int mt = 0; mt < 2; ++mt) {
                    s8v a = *(const s8v*)&Wlds[((((mt << 6) + ks) << 6) + lane) << 3];
                    acc[mt] = __builtin_amdgcn_mfma_f32_16x16x32_bf16(a, bfa[ks], acc[mt], 0, 0, 0);
                }
            #pragma unroll
            for (int ks = 0; ks < 32; ++ks)
                #pragma unroll
                for (int mt = 0; mt < 2; ++mt) {
                    s8v a = *(const s8v*)&Wlds[((((mt << 6) + 32 + ks) << 6) + lane) << 3];
                    acc[mt] = __builtin_amdgcn_mfma_f32_16x16x32_bf16(a, bfb[ks], acc[mt], 0, 0, 0);
                }
        }
        #pragma unroll
        for (int mt = 0; mt < NMT; ++mt)
            #pragma unroll
            for (int r = 0; r < 4; ++r) {
                int ci = (mt << 4) + ((lane >> 4) << 2) + r;  // gate-col local
                gatesLds[ci * 68 + brow] = acc[mt][r];
            }
        __syncthreads();

        // epilogue: 4 adjacent h-cols per thread, 8B packed h publish
        if (ep_active) {
            float ga[4][4];
            #pragma unroll
            for (int g = 0; g < 4; ++g)
                #pragma unroll
                for (int j = 0; j < 4; ++j)
                    ga[g][j] = gatesLds[(g * NH + ejq + j) * 68 + eb];
            if (IS_L0) {
                #pragma unroll
                for (int g = 0; g < 4; ++g) {
                    ga[g][0] += bf2f((bhalf)(g0pre[g].x & 0xffffu));
                    ga[g][1] += bf2f((bhalf)(g0pre[g].x >> 16));
                    ga[g][2] += bf2f((bhalf)(g0pre[g].y & 0xffffu));
                    ga[g][3] += bf2f((bhalf)(g0pre[g].y >> 16));
                }
            } else {
                #pragma unroll
                for (int g = 0; g < 4; ++g)
                    #pragma unroll
                    for (int j = 0; j < 4; ++j) ga[g][j] += breg[g][j];
            }
            float hv[4];
            #pragma unroll
            for (int j = 0; j < 4; ++j) {
                float cn = sigf(ga[1][j]) * creg[j] + sigf(ga[0][j]) * tanh_(ga[3][j]);
                creg[j] = cn;
                hv[j] = sigf(ga[2][j]) * tanh_(cn);
            }
            u32x2 hp;
            hp.x = (unsigned)f2bf(hv[0]) | ((unsigned)f2bf(hv[1]) << 16);
            hp.y = (unsigned)f2bf(hv[2]) | ((unsigned)f2bf(hv[3]) << 16);
            unsigned long long hpu = __builtin_bit_cast(unsigned long long, hp);
            const int ix = (eb << 10) + ehc;
            if (IS_L0) {
                __hip_atomic_store((unsigned long long*)(h0buf + (t % 3) * 65536 + ix), hpu,
                                   __ATOMIC_RELAXED, __HIP_MEMORY_SCOPE_AGENT);
            } else {
                __hip_atomic_store((unsigned long long*)(h1buf + (t & 1) * 65536 + ix), hpu,
                                   __ATOMIC_RELAXED, __HIP_MEMORY_SCOPE_AGENT);
                f32x4 ov = {hv[0], hv[1], hv[2], hv[3]};
                *(f32x4*)(out + (((size_t)t * 64 + eb) << 10) + ehc) = ov;
            }
        }
        // publish: all write-through stores acked, then flag (own cacheline)
        asm volatile("s_waitcnt vmcnt(0)" ::: "memory");
        __syncthreads();
        if (tid == 0)
            __hip_atomic_store(myflag, t + 1, __ATOMIC_RELAXED, __HIP_MEMORY_SCOPE_AGENT);
    }

    // persist c for next chunk / tail
    if (ep_active) {
        #pragma unroll
        for (int j = 0; j < 4; ++j) cws[(eb << 10) + ehc + j] = creg[j];
    }
}

__global__ __launch_bounds__(256, 1) void rec_k(
    const bhalf* __restrict__ W0T, const bhalf* __restrict__ W1T,
    const bhalf* __restrict__ G0, const float* __restrict__ bias1,
    bhalf* h0buf, bhalf* h1buf, float* c0ws, float* c1ws,
    int* done0, int* done1, float* out, int t0, int nsteps)
{
    __shared__ __align__(16) bhalf Wlds[65536];        // 128 KB swizzled weights
    __shared__ __align__(16) float gatesLds[64 * 68];  // 17 KB gate exchange
    const int tid = threadIdx.x;
    const int wg = blockIdx.x;
    if (wg < 64) {
        // layer0: 64 gate-cols (16 h-cols); swizzle to lane-linear frag order
        for (int it = 0; it < 32; ++it) {
            int e = (((it << 8) + tid) << 3);
            int ci = e >> 10, k0 = e & 1023;
            int n = ((ci >> 4) << 10) + (wg << 4) + (ci & 15);
            int mt = ci >> 4, m = ci & 15, ks = k0 >> 5, q = (k0 >> 3) & 3;
            int off = ((((mt << 5) + ks) << 6) + (q << 4) + m) << 3;
            *(s8v*)&Wlds[off] = *(const s8v*)(W0T + ((size_t)n << 10) + k0);
        }
        rec_loop<true>(Wlds, gatesLds, G0, bias1, h0buf, h1buf, c0ws,
                       done0, done1, out, t0, nsteps, wg);
    } else {
        int wg1 = wg - 64;
        // layer1: 32 gate-cols (8 h-cols), K=2048
        for (int it = 0; it < 32; ++it) {
            int e = (((it << 8) + tid) << 3);
            int ci = e >> 11, k0 = e & 2047;
            int n = ((ci >> 3) << 10) + (wg1 << 3) + (ci & 7);
            int mt = ci >> 4, m = ci & 15, ks = k0 >> 5, q = (k0 >> 3) & 3;
            int off = ((((mt << 6) + ks) << 6) + (q << 4) + m) << 3;
            *(s8v*)&Wlds[off] = *(const s8v*)(W1T + ((size_t)n << 11) + k0);
        }
        rec_loop<false>(Wlds, gatesLds, G0, bias1, h0buf, h1buf, c1ws,
                        done0, done1, out, t0, nsteps, wg1);
    }
}

// --------------------------------- tail -------------------------------------
__global__ __launch_bounds__(256) void tail_k(
    const bhalf* __restrict__ h0f, const bhalf* __restrict__ h1f,
    const float* __restrict__ c0, const float* __restrict__ c1, float* dst)
{
    int i = blockIdx.x * 256 + threadIdx.x;  // grid 512 -> 131072
    if (i >= 131072) return;
    int l = i >> 16, r = i & 65535;
    dst[i] = bf2f(l ? h1f[r] : h0f[r]);
    dst[131072 + i] = l ? c1[r] : c0[r];
}

// --------------------------------- host -------------------------------------
extern "C" void kernel_launch(void* const* d_in, const int* in_sizes, int n_in,
                              void* d_out, int out_size, void* d_ws, size_t ws_size,
                              hipStream_t stream) {
    const float* x    = (const float*)d_in[0];
    const float* Wih0 = (const float*)d_in[1];
    const float* bih0 = (const float*)d_in[2];
    const float* Whh0 = (const float*)d_in[3];
    const float* bhh0 = (const float*)d_in[4];
    const float* Wih1 = (const float*)d_in[5];
    const float* bih1 = (const float*)d_in[6];
    const float* Whh1 = (const float*)d_in[7];
    const float* bhh1 = (const float*)d_in[8];
    float* out = (float*)d_out;
    char* ws = (char*)d_ws;

    bhalf* WT0ih = (bhalf*)(ws);                    // [4096][1024] bf16
    bhalf* WT0hh = (bhalf*)(ws + 8388608);          // [4096][1024]
    bhalf* WT1   = (bhalf*)(ws + 16777216);         // [4096][2048] = [Wih1;Whh1]
    float* bias0 = (float*)(ws + 33554432);
    float* bias1 = (float*)(ws + 33570816);
    bhalf* h0buf = (bhalf*)(ws + 33587200);         // 3 x (64x1024)
    bhalf* h1buf = (bhalf*)(ws + 33980416);         // 2 x (64x1024)
    float* c0    = (float*)(ws + 34242560);
    float* c1    = (float*)(ws + 34504704);
    int*   done0 = (int*)(ws + 34766848);           // 64 x 32 ints (128B apart)
    int*   done1 = (int*)(ws + 34775040);           // 128 x 32 ints
    bhalf* G0    = (bhalf*)(ws + 34791424);         // [CHUNK*64][4096] bf16

    const size_t fixedSz = 34791424;
    int CHUNK = 8;
    for (int c = 512; c >= 8; c >>= 1)
        if (fixedSz + (size_t)c * 524288 <= ws_size) { CHUNK = c; break; }

    init_k<<<256, 256, 0, stream>>>(bih0, bhh0, bih1, bhh1, bias0, bias1,
                                    h0buf + 2 * 65536, h1buf + 1 * 65536, c0, c1, done0);
    transpose_k<<<1024, 256, 0, stream>>>(Wih0, WT0ih, 1024, 0);
    transpose_k<<<1024, 256, 0, stream>>>(Whh0, WT0hh, 1024, 0);
    transpose_k<<<1024, 256, 0, stream>>>(Wih1, WT1, 2048, 0);
    transpose_k<<<1024, 256, 0, stream>>>(Whh1, WT1, 2048, 1024);

    for (int t0 = 0; t0 < 512; t0 += CHUNK) {
        int bmCount = CHUNK / 2;
        g0gemm_k<<<bmCount * 32, 256, 0, stream>>>(x, WT0ih, bias0, G0, t0, bmCount);
        rec_k<<<192, 256, 0, stream>>>(WT0hh, WT1, G0, bias1, h0buf, h1buf,
                                       c0, c1, done0, done1, out, t0, CHUNK);
    }
    // final h: h0(511) in slot (511%3)=1 ; h1(511) in slot (511&1)=1
    tail_k<<<512, 256, 0, stream>>>(h0buf + 1 * 65536, h1buf + 1 * 65536,
                                    c0, c1, out + 33554432);
}